// Round 1
// 17452.321 us; speedup vs baseline: 1.2108x; 1.2108x over previous
//
#include <hip/hip_runtime.h>
#include <hip/hip_cooperative_groups.h>

namespace cg = cooperative_groups;

// Problem constants (match reference)
constexpr int kD   = 4096;   // hidden width
constexpr int kT   = 200;    // trajectory length
constexpr int kX   = 64;     // obs dim
constexpr int kEMB = 128;
constexpr int kH1  = 1024;
constexpr int kK   = 2048;   // top-k kept
constexpr int kBLK = 256;    // one block per CU (cooperative co-residency)
constexpr int kTHR = 1024;   // 16 waves/block
constexpr int kUPB = kD / kBLK;  // 16 LSTM units per block

// ---- Whh on-chip residency plan -------------------------------------------
// Each row (4096 cols) is split into 16 chunks of 256 cols (64 lanes x float4).
//   chunks [0,3)   : persistent in VGPRs  (48 VGPR/lane for 4 gate rows)
//   chunks [3,5)   : persistent in LDS    (128 KB/CU)
//   chunks [5,16)  : streamed each step   (184.5 MB footprint < 256 MB L3)
// First kPF streamed chunks are prefetched into registers BEFORE grid.sync so
// their latency overlaps the barrier (weight addresses don't depend on h).
constexpr int kNCH  = kD / 256;       // 16
constexpr int kREGc = 3;
constexpr int kLDSc = 2;
constexpr int kSTR0 = kREGc + kLDSc;  // 5
constexpr int kPF   = 2;              // prefetched streamed chunks

__device__ __forceinline__ float hsum4(float4 a) { return (a.x + a.y) + (a.z + a.w); }

__device__ __forceinline__ void fma4(float4& a, const float4 w, const float4 h) {
  a.x = fmaf(w.x, h.x, a.x); a.y = fmaf(w.y, h.y, a.y);
  a.z = fmaf(w.z, h.z, a.z); a.w = fmaf(w.w, h.w, a.w);
}

__device__ __forceinline__ float wave_sum(float s) {
#pragma unroll
  for (int off = 32; off > 0; off >>= 1) s += __shfl_xor(s, off, 64);
  return s;
}

__device__ __forceinline__ int wave_sum_i(int s) {
#pragma unroll
  for (int off = 32; off > 0; off >>= 1) s += __shfl_xor(s, off, 64);
  return s;
}

// order-preserving float->uint for atomic min/max over signed floats
__device__ __forceinline__ unsigned fenc(float f) {
  unsigned u = __float_as_uint(f);
  return (u & 0x80000000u) ? ~u : (u | 0x80000000u);
}
__device__ __forceinline__ float fdec(unsigned k) {
  return __uint_as_float((k & 0x80000000u) ? (k & 0x7FFFFFFFu) : ~k);
}

// dot(W[r,:], v) where v is staged in LDS as float4[1024]; result in all lanes
__device__ __forceinline__ float mv_row(const float* __restrict__ W, int r,
                                        const float4* sh4, int lane) {
  const float4* __restrict__ W4 = (const float4*)(W + (size_t)r * kD);
  float4 a = make_float4(0.f, 0.f, 0.f, 0.f);
#pragma unroll
  for (int c = 0; c < 16; ++c) {
    float4 wv = W4[c * 64 + lane];
    float4 hv = sh4[c * 64 + lane];
    fma4(a, wv, hv);
  }
  return wave_sum(hsum4(a));
}

__global__ __launch_bounds__(kTHR) void mgnet(
    const float* __restrict__ x, const float* __restrict__ emb_in,
    const float* __restrict__ Wih, const float* __restrict__ Whh,
    const float* __restrict__ lb,
    const float* __restrict__ emW1, const float* __restrict__ emb1,
    const float* __restrict__ emW2, const float* __restrict__ emb2,
    const float* __restrict__ fc0W, const float* __restrict__ fc0b,
    const float* __restrict__ condW, const float* __restrict__ condb,
    const float* __restrict__ fcW, const float* __restrict__ fcb,
    float* __restrict__ ws, float* __restrict__ out) {
  cg::grid_group grid = cg::this_grid();

  __shared__ float4 sh4[kD / 4];                 // 16 KB staging (h / matvec input)
  __shared__ float4 wl4[64 * (kLDSc * 64)];      // 128 KB persistent Whh chunks
  __shared__ float zs[16];                       // per-wave row values for min/max
  __shared__ int redi[16];                       // binarize count reduce

  const int bid = blockIdx.x;
  const int tid = threadIdx.x;
  const int w = tid >> 6;
  const int lane = tid & 63;

  // workspace layout (floats)
  float* h_g   = ws;                 // 4096  LSTM hidden (global exchange)
  float* h1v   = ws + kD;            // 1024
  float* ebd   = h1v + kH1;          // 4096  embedding (signed)
  float* actv  = ebd + kD;           // 4096  relu(embedding)
  float* vecA  = actv + kD;          // 4096  pre-bound raw
  float* rawv  = vecA + kD;          // 4096  bounded raw
  float* condv = rawv + kD;          // 4096
  unsigned* slots = (unsigned*)(condv + kD);  // [5][2] = {min,max} encoded

  // init min/max atomic slots (poisoned ws!); visible long before first use
  if (bid == 0 && tid < 5) {
    slots[2 * tid] = 0xFFFFFFFFu;
    slots[2 * tid + 1] = 0u;
  }

  // ---------------- Phase 1: LSTM (200 sequential steps) ----------------
  // wave w of block bid owns unit u; computes all 4 gate rows -> cell state in
  // registers. Whh rows are mostly pinned on-chip (VGPR+LDS), remainder
  // streamed from an L3-resident 184.5 MB footprint.
  const int u = bid * kUPB + w;
  const float4* __restrict__ W4g0 = (const float4*)(Whh + (size_t)(0 * kD + u) * kD);
  const float4* __restrict__ W4g1 = (const float4*)(Whh + (size_t)(1 * kD + u) * kD);
  const float4* __restrict__ W4g2 = (const float4*)(Whh + (size_t)(2 * kD + u) * kD);
  const float4* __restrict__ W4g3 = (const float4*)(Whh + (size_t)(3 * kD + u) * kD);
  const float wih0 = Wih[(size_t)(0 * kD + u) * kX + lane];
  const float wih1 = Wih[(size_t)(1 * kD + u) * kX + lane];
  const float wih2 = Wih[(size_t)(2 * kD + u) * kX + lane];
  const float wih3 = Wih[(size_t)(3 * kD + u) * kX + lane];
  const float b0 = lb[0 * kD + u], b1 = lb[1 * kD + u];
  const float b2 = lb[2 * kD + u], b3 = lb[3 * kD + u];

  // persistent VGPR-held chunks (static indexing only -> stays in registers)
  float4 wr0[kREGc], wr1[kREGc], wr2[kREGc], wr3[kREGc];
#pragma unroll
  for (int c = 0; c < kREGc; ++c) {
    const int idx = c * 64 + lane;
    wr0[c] = W4g0[idx]; wr1[c] = W4g1[idx]; wr2[c] = W4g2[idx]; wr3[c] = W4g3[idx];
  }
  // persistent LDS-held chunks (each wave owns rows w*4..w*4+3; no cross-wave use)
#pragma unroll
  for (int c = 0; c < kLDSc; ++c) {
    const int idx = (kREGc + c) * 64 + lane;
    wl4[(w * 4 + 0) * (kLDSc * 64) + c * 64 + lane] = W4g0[idx];
    wl4[(w * 4 + 1) * (kLDSc * 64) + c * 64 + lane] = W4g1[idx];
    wl4[(w * 4 + 2) * (kLDSc * 64) + c * 64 + lane] = W4g2[idx];
    wl4[(w * 4 + 3) * (kLDSc * 64) + c * 64 + lane] = W4g3[idx];
  }

  // prime the cross-barrier prefetch of the first kPF streamed chunks
  float4 p00, p01, p02, p03, p10, p11, p12, p13;
  {
    const int i0 = kSTR0 * 64 + lane;
    const int i1 = i0 + 64;
    p00 = W4g0[i0]; p01 = W4g1[i0]; p02 = W4g2[i0]; p03 = W4g3[i0];
    p10 = W4g0[i1]; p11 = W4g1[i1]; p12 = W4g2[i1]; p13 = W4g3[i1];
  }

  float cst = 0.f;
  const float4* hg4 = (const float4*)h_g;

  for (int t = 0; t < kT; ++t) {
    // stage h_{t-1} into LDS (h0 = 0; never trust poisoned ws at t==0)
    sh4[tid] = (t == 0) ? make_float4(0.f, 0.f, 0.f, 0.f) : hg4[tid];
    __syncthreads();

    float4 a0 = make_float4(0.f, 0.f, 0.f, 0.f), a1 = a0, a2 = a0, a3 = a0;

    // prefetched streamed chunks (loads were issued before the grid.sync)
    {
      const float4 hv0 = sh4[kSTR0 * 64 + lane];
      fma4(a0, p00, hv0); fma4(a1, p01, hv0); fma4(a2, p02, hv0); fma4(a3, p03, hv0);
      const float4 hv1 = sh4[(kSTR0 + 1) * 64 + lane];
      fma4(a0, p10, hv1); fma4(a1, p11, hv1); fma4(a2, p12, hv1); fma4(a3, p13, hv1);
    }
    // remaining streamed chunks
#pragma unroll
    for (int c = kSTR0 + kPF; c < kNCH; ++c) {
      const int idx = c * 64 + lane;
      const float4 hv = sh4[idx];
      const float4 w0 = W4g0[idx];
      const float4 w1 = W4g1[idx];
      const float4 w2 = W4g2[idx];
      const float4 w3 = W4g3[idx];
      fma4(a0, w0, hv); fma4(a1, w1, hv); fma4(a2, w2, hv); fma4(a3, w3, hv);
    }
    // VGPR-held chunks
#pragma unroll
    for (int c = 0; c < kREGc; ++c) {
      const float4 hv = sh4[c * 64 + lane];
      fma4(a0, wr0[c], hv); fma4(a1, wr1[c], hv);
      fma4(a2, wr2[c], hv); fma4(a3, wr3[c], hv);
    }
    // LDS-held chunks
#pragma unroll
    for (int c = 0; c < kLDSc; ++c) {
      const float4 hv = sh4[(kREGc + c) * 64 + lane];
      const float4 w0 = wl4[(w * 4 + 0) * (kLDSc * 64) + c * 64 + lane];
      const float4 w1 = wl4[(w * 4 + 1) * (kLDSc * 64) + c * 64 + lane];
      const float4 w2 = wl4[(w * 4 + 2) * (kLDSc * 64) + c * 64 + lane];
      const float4 w3 = wl4[(w * 4 + 3) * (kLDSc * 64) + c * 64 + lane];
      fma4(a0, w0, hv); fma4(a1, w1, hv); fma4(a2, w2, hv); fma4(a3, w3, hv);
    }

    // fold Wih contribution per-lane, then one butterfly per gate
    const float xt = x[t * kX + lane];
    float s0 = wave_sum(hsum4(a0) + wih0 * xt);
    float s1 = wave_sum(hsum4(a1) + wih1 * xt);
    float s2 = wave_sum(hsum4(a2) + wih2 * xt);
    float s3 = wave_sum(hsum4(a3) + wih3 * xt);

    const float zi = s0 + b0, zf = s1 + b1, zg = s2 + b2, zo = s3 + b3;
    const float ig = 1.f / (1.f + expf(-zi));
    const float fg = 1.f / (1.f + expf(-zf));
    const float gg = tanhf(zg);
    const float og = 1.f / (1.f + expf(-zo));
    cst = fg * cst + ig * gg;
    const float hval = og * tanhf(cst);
    if (lane == 0) h_g[u] = hval;

    // issue next step's first streamed-chunk loads BEFORE the barrier so their
    // latency overlaps the barrier spin (addresses are h-independent).
    {
      const int i0 = kSTR0 * 64 + lane;
      const int i1 = i0 + 64;
      p00 = W4g0[i0]; p01 = W4g1[i0]; p02 = W4g2[i0]; p03 = W4g3[i0];
      p10 = W4g0[i1]; p11 = W4g1[i1]; p12 = W4g2[i1]; p13 = W4g3[i1];
    }
    grid.sync();  // publish h_t to all blocks (also block-level WAR barrier)
  }

  // ---------------- Phase 2: em_base MLP ----------------
  {
    const int gw = bid * 16 + w;  // 0..4095
    if (gw < kH1) {
      const float w0 = emW1[(size_t)gw * kEMB + lane];
      const float w1 = emW1[(size_t)gw * kEMB + 64 + lane];
      const float s = wave_sum(fmaf(w0, emb_in[lane], w1 * emb_in[64 + lane]));
      if (lane == 0) h1v[gw] = fmaxf(s + emb1[gw], 0.f);
    }
  }
  grid.sync();
  {
    if (tid < kH1 / 4) sh4[tid] = ((const float4*)h1v)[tid];
    __syncthreads();
    const int r = bid * 16 + w;
    const float4* W4e = (const float4*)(emW2 + (size_t)r * kH1);
    float4 a = make_float4(0.f, 0.f, 0.f, 0.f);
#pragma unroll
    for (int c = 0; c < 4; ++c) {
      const float4 wv = W4e[c * 64 + lane];
      const float4 hv = sh4[c * 64 + lane];
      fma4(a, wv, hv);
    }
    const float s = wave_sum(hsum4(a));
    if (lane == 0) {
      const float e = (s + emb2[r]) * h_g[r];  // h_g == LSTM "out"
      ebd[r] = e;
      actv[r] = fmaxf(e, 0.f);
    }
  }
  grid.sync();

  // ---------------- Phase 3: mask chain (fc0 + 4x (cond, fc)) ----------------
  const int r = bid * 16 + w;
  const float* vsrc = actv;
  const float* Wcur = fc0W;
  const float* bcur = fc0b;
  for (int m = 0; m <= 4; ++m) {
    // bound matvec -> vecA, block-level min/max -> device atomics
    sh4[tid] = ((const float4*)vsrc)[tid];
    __syncthreads();
    const float z = mv_row(Wcur, r, sh4, lane) + bcur[r];
    if (lane == 0) { vecA[r] = z; zs[w] = z; }
    __syncthreads();
    if (tid == 0) {
      float mn = zs[0], mx = zs[0];
#pragma unroll
      for (int i = 1; i < 16; ++i) { mn = fminf(mn, zs[i]); mx = fmaxf(mx, zs[i]); }
      atomicMin(&slots[2 * m], fenc(mn));
      atomicMax(&slots[2 * m + 1], fenc(mx));
    }
    grid.sync();
    // normalize: raw = (a - mn) / (mx - mn); write probs row
    if (bid < 4) {
      const int i = bid * kTHR + tid;
      const float mn = fdec(slots[2 * m]);
      const float mx = fdec(slots[2 * m + 1]);
      const float val = (vecA[i] - mn) / (mx - mn);
      rawv[i] = val;
      out[m * kD + i] = val;
    }
    grid.sync();

    if (m == 4) break;
    // cond layer m: relu((raw @ condW^T + condb) * embedding)
    sh4[tid] = ((const float4*)rawv)[tid];
    __syncthreads();
    const float zc = mv_row(condW + (size_t)m * kD * kD, r, sh4, lane) + condb[m * kD + r];
    if (lane == 0) condv[r] = fmaxf(zc * ebd[r], 0.f);
    grid.sync();
    vsrc = condv;
    Wcur = fcW + (size_t)m * kD * kD;
    bcur = fcb + m * kD;
  }

  // ---------------- Phase 4: binarize (exact top-K threshold) ----------------
  // probs >= 0 -> raw float bits are order-preserving uints. Radix binary
  // search for the largest v with count(key >= v) >= K == the K-th largest.
  if (bid < 5) {
    const float4 pv = ((const float4*)(out + bid * kD))[tid];
    const unsigned k0 = __float_as_uint(pv.x);
    const unsigned k1 = __float_as_uint(pv.y);
    const unsigned k2 = __float_as_uint(pv.z);
    const unsigned k3 = __float_as_uint(pv.w);
    unsigned cur = 0u;
    for (int bit = 31; bit >= 0; --bit) {
      const unsigned cand = cur | (1u << bit);
      int cnt = (int)(k0 >= cand) + (int)(k1 >= cand) +
                (int)(k2 >= cand) + (int)(k3 >= cand);
      cnt = wave_sum_i(cnt);
      if (lane == 0) redi[w] = cnt;
      __syncthreads();
      int total = 0;
#pragma unroll
      for (int i = 0; i < 16; ++i) total += redi[i];
      if (total >= kK) cur = cand;
      __syncthreads();
    }
    float4 bo;
    bo.x = (k0 >= cur && k0 != 0u) ? 1.f : 0.f;
    bo.y = (k1 >= cur && k1 != 0u) ? 1.f : 0.f;
    bo.z = (k2 >= cur && k2 != 0u) ? 1.f : 0.f;
    bo.w = (k3 >= cur && k3 != 0u) ? 1.f : 0.f;
    ((float4*)(out + 5 * kD + bid * kD))[tid] = bo;
  }
}

extern "C" void kernel_launch(void* const* d_in, const int* in_sizes, int n_in,
                              void* d_out, int out_size, void* d_ws, size_t ws_size,
                              hipStream_t stream) {
  const float* x     = (const float*)d_in[0];
  const float* embi  = (const float*)d_in[1];
  const float* Wih   = (const float*)d_in[2];
  const float* Whh   = (const float*)d_in[3];
  const float* lb    = (const float*)d_in[4];
  const float* emW1  = (const float*)d_in[5];
  const float* emb1  = (const float*)d_in[6];
  const float* emW2  = (const float*)d_in[7];
  const float* emb2  = (const float*)d_in[8];
  const float* fc0W  = (const float*)d_in[9];
  const float* fc0b  = (const float*)d_in[10];
  const float* condW = (const float*)d_in[11];
  const float* condb = (const float*)d_in[12];
  const float* fcW   = (const float*)d_in[13];
  const float* fcb   = (const float*)d_in[14];
  float* ws  = (float*)d_ws;
  float* out = (float*)d_out;

  void* args[] = {&x, &embi, &Wih, &Whh, &lb, &emW1, &emb1, &emW2, &emb2,
                  &fc0W, &fc0b, &condW, &condb, &fcW, &fcb, &ws, &out};
  (void)in_sizes; (void)n_in; (void)out_size; (void)ws_size;
  hipLaunchCooperativeKernel(mgnet, dim3(kBLK), dim3(kTHR), args, 0u, stream);
}